// Round 3
// baseline (391.268 us; speedup 1.0000x reference)
//
#include <hip/hip_runtime.h>
#include <hip/hip_cooperative_groups.h>

namespace cg = cooperative_groups;

// Problem constants (from reference)
#define BB 4
#define CC 64
#define NXX 432
#define NYY 496
#define GG (NXX * NYY)          // 214272 cells per batch
#define PP 80000                // total pillars (B * P_PER)

typedef float v4f __attribute__((ext_vector_type(4)));

// Reference reduces to a dense BEV scatter: prob_buf is zeros (kept bug) so
// p == 0 -> out = spatial. Output [B,C,NY,NX] = pillar_features scattered.
//
// r0-r2 established: gather is NOT latency-bound (2x occupancy neutral), NOT
// store-path-bound (nt vs normal neutral), NOT read-amp-bound (3.4 vs 27 MB
// map traffic neutral). Remaining controllable lever: dispatch count. This
// version fuses init->scatter->gather into ONE cooperative launch with two
// grid.sync()s, removing 2 dispatch boundaries from the measured window.

// Workspace layout: [0, B*G) int cell->pillar map, then 64 floats of zeros
// (a "zero pillar row" that empty cells gather from).
#define ZROW_INT_OFF (BB * GG)

__global__ void __launch_bounds__(256, 4) k_fused(const float* __restrict__ pf,
                                                  const int* __restrict__ coords,
                                                  int* __restrict__ map,
                                                  float* __restrict__ out) {
    cg::grid_group grid = cg::this_grid();
    const int tid = blockIdx.x * blockDim.x + threadIdx.x;
    const int nthr = gridDim.x * blockDim.x;
    const int n4 = (BB * GG) / 4;                    // 214272

    // ---- Phase 1: map = -1 everywhere; zero-row = 0 ----
    for (int i = tid; i < n4; i += nthr)
        ((int4*)map)[i] = make_int4(-1, -1, -1, -1);
    if (tid < 16)                                    // 64 floats = 16 int4
        ((int4*)(map + ZROW_INT_OFF))[tid] = make_int4(0, 0, 0, 0);

    grid.sync();

    // ---- Phase 2: scatter pillar ids (coords unique per batch) ----
    for (int i = tid; i < PP; i += nthr) {
        int4 cd = ((const int4*)coords)[i];          // (b, z, y, x), z == 0
        map[cd.x * GG + cd.y + cd.z * NXX + cd.w] = i;
    }

    grid.sync();

    // ---- Phase 3: gather. Quad of cells x all 64 channels (r2 body) ----
    const v4f* pf4 = (const v4f*)pf;                 // pf rows: 64 floats = 16 vec4
    const v4f* z4  = (const v4f*)(map + ZROW_INT_OFF);

    for (int t = tid; t < n4; t += nthr) {
        int cellBase = t * 4;
        int b = cellBase / GG;                       // G%4==0: quad never crosses batch
        int cellInB = cellBase - b * GG;

        int4 pids = ((const int4*)map)[t];
        const v4f* p0 = (pids.x >= 0) ? (pf4 + pids.x * 16) : z4;
        const v4f* p1 = (pids.y >= 0) ? (pf4 + pids.y * 16) : z4;
        const v4f* p2 = (pids.z >= 0) ? (pf4 + pids.z * 16) : z4;
        const v4f* p3 = (pids.w >= 0) ? (pf4 + pids.w * 16) : z4;

        float* outBase = out + (size_t)(b * CC) * GG + cellInB;

        #pragma unroll
        for (int g = 0; g < 4; ++g) {
            v4f r[4][4];
            #pragma unroll
            for (int j = 0; j < 4; ++j) {
                r[j][0] = p0[g * 4 + j];
                r[j][1] = p1[g * 4 + j];
                r[j][2] = p2[g * 4 + j];
                r[j][3] = p3[g * 4 + j];
            }
            #pragma unroll
            for (int j = 0; j < 4; ++j) {
                int c0 = (g * 4 + j) * 4;            // first of 4 channels
                v4f w0 = (v4f){r[j][0].x, r[j][1].x, r[j][2].x, r[j][3].x};
                v4f w1 = (v4f){r[j][0].y, r[j][1].y, r[j][2].y, r[j][3].y};
                v4f w2 = (v4f){r[j][0].z, r[j][1].z, r[j][2].z, r[j][3].z};
                v4f w3 = (v4f){r[j][0].w, r[j][1].w, r[j][2].w, r[j][3].w};

                *(v4f*)(outBase + (size_t)(c0 + 0) * GG) = w0;
                *(v4f*)(outBase + (size_t)(c0 + 1) * GG) = w1;
                *(v4f*)(outBase + (size_t)(c0 + 2) * GG) = w2;
                *(v4f*)(outBase + (size_t)(c0 + 3) * GG) = w3;
            }
        }
    }
}

extern "C" void kernel_launch(void* const* d_in, const int* in_sizes, int n_in,
                              void* d_out, int out_size, void* d_ws, size_t ws_size,
                              hipStream_t stream) {
    const float* pf     = (const float*)d_in[0];     // [80000, 64] f32
    const int*   coords = (const int*)d_in[7];       // [80000, 4] i32 (b,z,y,x)
    float*       out    = (float*)d_out;             // [B, C, NY, NX] f32
    int*         map    = (int*)d_ws;                // [B*G] i32 + 64-float zero row

    // Co-resident grid sizing: occupancy query once (host-side, capture-safe),
    // 256 CUs on MI355X. __launch_bounds__(256,4) targets 4 blocks/CU.
    static int nBlocks = 0;
    if (nBlocks == 0) {
        int nb = 0;
        hipError_t e = hipOccupancyMaxActiveBlocksPerMultiprocessor(&nb, k_fused, 256, 0);
        if (e != hipSuccess || nb < 1) nb = 2;       // conservative fallback
        if (nb > 8) nb = 8;
        nBlocks = nb * 256;
    }

    void* args[] = {(void*)&pf, (void*)&coords, (void*)&map, (void*)&out};
    hipLaunchCooperativeKernel((const void*)k_fused, dim3(nBlocks), dim3(256),
                               args, 0, stream);
}

// Round 5
// 249.785 us; speedup vs baseline: 1.5664x; 1.5664x over previous
//
#include <hip/hip_runtime.h>
#include <hip/hip_bf16.h>

// Problem constants (from reference)
#define BB 4
#define CC 64
#define NXX 432
#define NYY 496
#define GG (NXX * NYY)          // 214272 cells per batch
#define PP 80000                // total pillars (B * P_PER)

typedef float v4f __attribute__((ext_vector_type(4)));

// Reference reduces to a dense BEV scatter: prob_buf is zeros (kept bug) so
// p == 0 -> out = spatial. Output [B,C,NY,NX] = pillar_features scattered.
//
// Session ledger (r0-r4):
//  - Traffic is at floor: FETCH 20.8 MB + WRITE 220 MB = 247 MB (r3 counters),
//    ~39 us at 6.3 TB/s.
//  - NOT latency-bound (r1: 2x occupancy neutral), NOT store-path-bound
//    (r2: nt vs normal neutral), NOT read-amp-bound (r2 neutral).
//  - Cooperative fusion (r3/r4): grid.sync does not reliably order plain
//    stores across XCD L2s for this pattern (r4 failed with stale map reads);
//    dispatch boundaries below provide the ordering for free.
//  - Measured window is dominated by the harness's 877 MB poison fill
//    (~131 us @ 6.5 TB/s, top dispatch every iteration).
// This is the best measured passing variant (r0: 247.0 us).

// Kernel 1: init cell->pillar map to -1.
__global__ void k_init_map(int* __restrict__ map) {
    int i = blockIdx.x * blockDim.x + threadIdx.x;   // one int4 per thread
    const int n4 = (BB * GG) / 4;                    // 214272
    if (i < n4) {
        ((int4*)map)[i] = make_int4(-1, -1, -1, -1);
    }
}

// Kernel 2: scatter pillar ids into the map (coords unique per batch).
__global__ void k_scatter_ids(const int* __restrict__ coords, int* __restrict__ map) {
    int i = blockIdx.x * blockDim.x + threadIdx.x;
    if (i < PP) {
        int4 cd = ((const int4*)coords)[i];          // (b, z, y, x), z == 0
        int g = cd.x * GG + cd.y + cd.z * NXX + cd.w;
        map[g] = i;
    }
}

// Kernel 3: gather. Thread = 4 consecutive cells x 16 channels (grid.y slice).
// Per thread: 1 int4 map read, 16 independent float4 loads, 16 float4 nt
// stores -- few long-latency ops per wave, 4x the waves for memory-level
// parallelism.
__global__ void __launch_bounds__(256) k_gather(const float* __restrict__ pf,
                                                const int* __restrict__ map,
                                                float* __restrict__ out) {
    int t = blockIdx.x * blockDim.x + threadIdx.x;   // cell-quad id
    const int nGroups = (BB * GG) / 4;               // 214272 = 837*256 exactly
    if (t >= nGroups) return;

    int cellBase = t * 4;
    int b = cellBase / GG;                           // G%4==0: quad never crosses batch
    int cellInB = cellBase - b * GG;

    int4 pids = ((const int4*)map)[t];
    const v4f* pf4 = (const v4f*)pf;                 // pf rows: 64 floats = 16 vec4

    bool v0 = pids.x >= 0, v1 = pids.y >= 0, v2 = pids.z >= 0, v3 = pids.w >= 0;
    int i0 = (v0 ? pids.x : 0) * 16;
    int i1 = (v1 ? pids.y : 0) * 16;
    int i2 = (v2 ? pids.z : 0) * 16;
    int i3 = (v3 ? pids.w : 0) * 16;

    const v4f zero = (v4f)(0.f);
    int qBase = blockIdx.y * 4;                      // this slice: q = qBase..qBase+3
    float* outBase = out + (size_t)(b * CC) * GG + cellInB;

    // Issue all 16 loads up front (independent, unconditional -> pipelined).
    v4f r[4][4];
    #pragma unroll
    for (int j = 0; j < 4; ++j) {
        r[j][0] = pf4[i0 + qBase + j];
        r[j][1] = pf4[i1 + qBase + j];
        r[j][2] = pf4[i2 + qBase + j];
        r[j][3] = pf4[i3 + qBase + j];
    }

    #pragma unroll
    for (int j = 0; j < 4; ++j) {
        v4f r0 = v0 ? r[j][0] : zero;
        v4f r1 = v1 ? r[j][1] : zero;
        v4f r2 = v2 ? r[j][2] : zero;
        v4f r3 = v3 ? r[j][3] : zero;

        int c0 = (qBase + j) * 4;                    // first of 4 channels
        v4f w0 = (v4f){r0.x, r1.x, r2.x, r3.x};
        v4f w1 = (v4f){r0.y, r1.y, r2.y, r3.y};
        v4f w2 = (v4f){r0.z, r1.z, r2.z, r3.z};
        v4f w3 = (v4f){r0.w, r1.w, r2.w, r3.w};

        __builtin_nontemporal_store(w0, (v4f*)(outBase + (size_t)(c0 + 0) * GG));
        __builtin_nontemporal_store(w1, (v4f*)(outBase + (size_t)(c0 + 1) * GG));
        __builtin_nontemporal_store(w2, (v4f*)(outBase + (size_t)(c0 + 2) * GG));
        __builtin_nontemporal_store(w3, (v4f*)(outBase + (size_t)(c0 + 3) * GG));
    }
}

extern "C" void kernel_launch(void* const* d_in, const int* in_sizes, int n_in,
                              void* d_out, int out_size, void* d_ws, size_t ws_size,
                              hipStream_t stream) {
    const float* pf     = (const float*)d_in[0];     // [80000, 64] f32
    const int*   coords = (const int*)d_in[7];       // [80000, 4] i32 (b,z,y,x)
    float*       out    = (float*)d_out;             // [B, C, NY, NX] f32
    int*         map    = (int*)d_ws;                // [B*G] i32 cell->pillar (3.43 MB)

    const int n4 = (BB * GG) / 4;                    // 214272
    k_init_map<<<dim3((n4 + 255) / 256), dim3(256), 0, stream>>>(map);
    k_scatter_ids<<<dim3((PP + 255) / 256), dim3(256), 0, stream>>>(coords, map);

    const int nGroups = (BB * GG) / 4;               // 214272 = 837 * 256 exactly
    dim3 grid((nGroups + 255) / 256, 4);             // 837 x 4 blocks, 16 ch each
    k_gather<<<grid, dim3(256), 0, stream>>>(pf, map, out);
}